// Round 6
// baseline (265.078 us; speedup 1.0000x reference)
//
#include <hip/hip_runtime.h>

// Problem constants
#define BB   128
#define DD   2048
#define NN   2048
#define LL   4
#define OUTN 1024
#define JBQ  32                // 16-k groups per K-quarter (512 k / quarter)
#define NDIG 5                 // base-128 digit planes (bias 2^34, scale 2^-33)

typedef double double4v __attribute__((ext_vector_type(4)));
typedef int    int4v    __attribute__((ext_vector_type(4)));
typedef char   char4v   __attribute__((ext_vector_type(4)));

// ---------------------------------------------------------------------------
// W digitization, layers 1..3 in ONE launch: W fp32 -> 5 non-negative
// base-128 digit planes of V' = rint(W * 2^33) + 2^34  (digits in [0,127],
// sign-safe for i8 MFMA).  TILED layout (R4-proven):
//   Wd[l][j][nsup:64][kc:32][cc:32][kk:64]   (2 KB tiles)
// ---------------------------------------------------------------------------
__global__ __launch_bounds__(256) void wdig5_kernel(
    const float* __restrict__ W1, signed char* __restrict__ Wd)
{
    const size_t DP = (size_t)NN * DD;
    size_t i  = (size_t)blockIdx.x * 256 + threadIdx.x;   // over 3*DP/4
    int    l  = (int)(i / (DP / 4));
    size_t e4 = i - (size_t)l * (DP / 4);
    int n = (int)(e4 >> 9);
    int k = (int)(e4 & 511) * 4;
    float4 w = *(const float4*)(W1 + (size_t)l * DP + (size_t)n * DD + k);
    const float wv[4] = {w.x, w.y, w.z, w.w};
    unsigned long long V[4];
    #pragma unroll
    for (int e = 0; e < 4; ++e)
        V[e] = (unsigned long long)(__double2ll_rn((double)wv[e] * 0x1p33)
                                    + (1LL << 34));
    signed char* base = Wd + (size_t)l * 5 * DP
                      + (size_t)(n >> 5) * 65536 + (size_t)(k >> 6) * 2048
                      + (n & 31) * 64 + (k & 63);
    #pragma unroll
    for (int j = 0; j < NDIG; ++j) {
        char4v p = { (char)((V[0] >> (7 * j)) & 127),
                     (char)((V[1] >> (7 * j)) & 127),
                     (char)((V[2] >> (7 * j)) & 127),
                     (char)((V[3] >> (7 * j)) & 127) };
        *(char4v*)(base + (size_t)j * DP) = p;
    }
}

// ---------------------------------------------------------------------------
// Barrier-free fused layer kernel, fp64 MFMA path (layer 0 / fallback).
// R6 change: generalized source addressing src[r*sR + bcol*sB] so layer 0
// reads x DIRECTLY ((sR,sB)=(1,DD), idx=axon0) -> gather0 kernel eliminated.
// Fallback layers use (sR,sB)=(BB,1) on the float ping-pong buffers.
// ---------------------------------------------------------------------------
__global__ __launch_bounds__(256, 2) void layer_kernel(
    const float* __restrict__ src,
    const int*   __restrict__ idx,    // nullptr => identity rows
    int sR, int sB,
    const float* __restrict__ Wl,     // [n][k] row-major
    const float* __restrict__ thresholds, int l,
    const int*   __restrict__ Tptr,
    float* __restrict__ dst, signed char* __restrict__ c8T, int isLast)
{
    __shared__ double red[4 * 64 * 8];   // 16 KB, epilogue only

    const int t    = threadIdx.x;
    const int wq   = t >> 6;             // K-quarter 0..3
    const int lane = t & 63;
    const int q    = lane >> 4;
    const int c    = lane & 15;

    const int g     = blockIdx.x;        // 0..511
    const int btile = (g >> 3) & 7;      // b-replicas of one nsup: same XCD (mod 8)
    const int nsup  = (g & 7) | ((g >> 6) << 3);
    const int n0    = nsup * 32;
    const int bcol  = btile * 16 + c;
    const size_t bo = (size_t)bcol * sB; // source column offset

    // ---- runtime D-layout probe (layout-agnostic epilogue), f64-native ----
    double4v pr = {0., 0., 0., 0.}, pcv = {0., 0., 0., 0.};
    pr  = __builtin_amdgcn_mfma_f64_16x16x4f64(0.25 * (double)c, 1.0, pr, 0, 0, 0);
    pcv = __builtin_amdgcn_mfma_f64_16x16x4f64(0.25, (double)c, pcv, 0, 0, 0);
    int rowD[4], colD[4];
    #pragma unroll
    for (int r = 0; r < 4; ++r) {
        rowD[r] = (int)(pr[r] + 0.25);
        colD[r] = (int)(pcv[r] + 0.25);
    }

    double4v acc0[4] = {{0.,0.,0.,0.},{0.,0.,0.,0.},{0.,0.,0.,0.},{0.,0.,0.,0.}};
    double4v acc1[4] = {{0.,0.,0.,0.},{0.,0.,0.,0.},{0.,0.,0.,0.},{0.,0.,0.,0.}};

    const int    kbase = wq * (DD / 4);  // 512 k per quarter
    const float* wb0   = Wl + (size_t)(n0 + c) * DD + kbase + 4 * q;
    const float* wb1   = wb0 + (size_t)16 * DD;
    const int*   ibase = idx ? (idx + kbase + 4 * q) : nullptr;

    float4 wv0[4], wv1[4];   // W pipelines (2 n-rows), static slots
    float4 sv[4];            // src pipeline, static slots
    int4   iv[4];            // idx pipeline, static slots

    // ---- prologue: groups 0..3 ----
    #pragma unroll
    for (int p = 0; p < 4; ++p) {
        wv0[p] = *(const float4*)(wb0 + 16 * p);
        wv1[p] = *(const float4*)(wb1 + 16 * p);
    }
    #pragma unroll
    for (int p = 0; p < 4; ++p) {
        int r0, r1, r2, r3;
        if (ibase) {
            int4 iv0 = *(const int4*)(ibase + 16 * p);
            r0 = iv0.x; r1 = iv0.y; r2 = iv0.z; r3 = iv0.w;
        } else {
            int kb = kbase + 16 * p + 4 * q;
            r0 = kb; r1 = kb + 1; r2 = kb + 2; r3 = kb + 3;
        }
        sv[p].x = src[(size_t)r0 * sR + bo];
        sv[p].y = src[(size_t)r1 * sR + bo];
        sv[p].z = src[(size_t)r2 * sR + bo];
        sv[p].w = src[(size_t)r3 * sR + bo];
    }
    if (ibase) {
        #pragma unroll
        for (int p = 0; p < 4; ++p) iv[p] = *(const int4*)(ibase + 16 * (4 + p));
    }

    // ---- barrier-free K-loop: 8 iterations x 4 static-slot groups ----
    for (int u = 0; u < JBQ / 4; ++u) {
        #pragma unroll
        for (int gg = 0; gg < 4; ++gg) {
            float4 w0 = wv0[gg];
            float4 w1 = wv1[gg];
            float4 s  = sv[gg];

            int jn = 4 * u + 4 + gg; if (jn > JBQ - 1) jn = JBQ - 1;
            wv0[gg] = *(const float4*)(wb0 + 16 * jn);
            wv1[gg] = *(const float4*)(wb1 + 16 * jn);

            int r0, r1, r2, r3;
            if (ibase) {
                int4 ivv = iv[gg];
                r0 = ivv.x; r1 = ivv.y; r2 = ivv.z; r3 = ivv.w;
            } else {
                int kb = kbase + 16 * jn + 4 * q;
                r0 = kb; r1 = kb + 1; r2 = kb + 2; r3 = kb + 3;
            }
            sv[gg].x = src[(size_t)r0 * sR + bo];
            sv[gg].y = src[(size_t)r1 * sR + bo];
            sv[gg].z = src[(size_t)r2 * sR + bo];
            sv[gg].w = src[(size_t)r3 * sR + bo];

            if (ibase) {
                int jm = 4 * u + 8 + gg; if (jm > JBQ - 1) jm = JBQ - 1;
                iv[gg] = *(const int4*)(ibase + 16 * jm);
            }

            acc0[0] = __builtin_amdgcn_mfma_f64_16x16x4f64((double)w0.x, (double)s.x, acc0[0], 0, 0, 0);
            acc1[0] = __builtin_amdgcn_mfma_f64_16x16x4f64((double)w1.x, (double)s.x, acc1[0], 0, 0, 0);
            acc0[1] = __builtin_amdgcn_mfma_f64_16x16x4f64((double)w0.y, (double)s.y, acc0[1], 0, 0, 0);
            acc1[1] = __builtin_amdgcn_mfma_f64_16x16x4f64((double)w1.y, (double)s.y, acc1[1], 0, 0, 0);
            acc0[2] = __builtin_amdgcn_mfma_f64_16x16x4f64((double)w0.z, (double)s.z, acc0[2], 0, 0, 0);
            acc1[2] = __builtin_amdgcn_mfma_f64_16x16x4f64((double)w1.z, (double)s.z, acc1[2], 0, 0, 0);
            acc0[3] = __builtin_amdgcn_mfma_f64_16x16x4f64((double)w0.w, (double)s.w, acc0[3], 0, 0, 0);
            acc1[3] = __builtin_amdgcn_mfma_f64_16x16x4f64((double)w1.w, (double)s.w, acc1[3], 0, 0, 0);
        }
    }

    double4v a0 = (acc0[0] + acc0[1]) + (acc0[2] + acc0[3]);
    double4v a1 = (acc1[0] + acc1[1]) + (acc1[2] + acc1[3]);

    {
        double* my = red + ((size_t)wq * 64 + lane) * 8;
        #pragma unroll
        for (int r = 0; r < 4; ++r) { my[r] = a0[r]; my[4 + r] = a1[r]; }
    }
    __syncthreads();
    if (wq < 2) {
        const int off = wq * 4;
        double a[4];
        #pragma unroll
        for (int r = 0; r < 4; ++r) {
            a[r] =  red[((size_t)0 * 64 + lane) * 8 + off + r];
            a[r] += red[((size_t)1 * 64 + lane) * 8 + off + r];
            a[r] += red[((size_t)2 * 64 + lane) * 8 + off + r];
            a[r] += red[((size_t)3 * 64 + lane) * 8 + off + r];
        }

        const double th = (double)thresholds[l];
        const int T = *Tptr;
        const float sc = isLast ? 1.0f : (1.0f / (float)T);
        double m0 = 0., m1 = 0., m2 = 0., m3 = 0.;
        int c0 = 0, c1 = 0, c2 = 0, c3 = 0;
        for (int tt = 0; tt < T; ++tt) {
            m0 += a[0]; if (m0 > th) { c0++; m0 -= th; }
            m1 += a[1]; if (m1 > th) { c1++; m1 -= th; }
            m2 += a[2]; if (m2 > th) { c2++; m2 -= th; }
            m3 += a[3]; if (m3 > th) { c3++; m3 -= th; }
        }
        int cnt[4] = {c0, c1, c2, c3};
        #pragma unroll
        for (int r = 0; r < 4; ++r) {
            int n = n0 + 16 * wq + rowD[r];
            int b = btile * 16 + colD[r];
            dst[(size_t)n * BB + b] = (float)cnt[r] * sc;
            if (c8T) c8T[(size_t)b * NN + n] = (signed char)cnt[r];
        }
    }
}

// ---------------------------------------------------------------------------
// Integer-exact layer kernel (layers 1..3), base-128 digits, TILED A,
// R6 change: the spike GATHER is fused into the kernel prologue -- idx goes
// to LDS (coalesced), counts are gathered from the previous layer's c8
// (L1/L2-resident, 256 KB) into a 32 KB LDS B-tile; K-loop B-fragments come
// from LDS (ds_read_b128, conflict-free 1KB/wave partition).  Eliminates the
// separate gather8 kernel (+its HBM round-trip and ~10us dispatch gap).
// K-loop / digit math / probes identical to R5-proven kernel.
// ---------------------------------------------------------------------------
__global__ __launch_bounds__(256, 2) void layer_i8_kernel(
    const signed char* __restrict__ c8,    // prev counts [b][n] (b-major rows)
    const int*   __restrict__ idx,         // this layer's axon_idx [DD]
    const signed char* __restrict__ Wd5,   // 5 tiled digit planes, stride DP
    const float* __restrict__ thresholds, int l,
    const int*   __restrict__ Tptr,
    float* __restrict__ dst, signed char* __restrict__ c8T, int isLast)
{
    __shared__ double red[4 * 64 * 8];                    // 16 KB
    alignas(16) __shared__ signed char btl[32 * 16 * 64]; // 32 KB [ck][b16][kk]
    alignas(16) __shared__ int kidx[DD];                  // 8 KB

    const int t    = threadIdx.x;
    const int wq   = t >> 6;
    const int lane = t & 63;
    const int q    = lane >> 4;
    const int c    = lane & 15;

    const int g     = blockIdx.x;
    const int btile = (g >> 3) & 7;
    const int nsup  = (g & 7) | ((g >> 6) << 3);
    const int n0    = nsup * 32;

    // ---- fused gather prologue ----
    {   // idx -> LDS, coalesced (512 int4 / 256 threads)
        const int4* ip = (const int4*)idx;
        int4* kp = (int4*)kidx;
        kp[t]       = ip[t];
        kp[t + 256] = ip[t + 256];
    }
    __syncthreads();
    {   // gather 16 count-rows into tiled LDS B: btl[j][b][kk]
        const int b = t >> 4, m = t & 15;
        const signed char* c8row = c8 + (size_t)(btile * 16 + b) * NN;
        #pragma unroll 4
        for (int j = 0; j < 32; ++j) {
            int4 id = *(const int4*)(kidx + m * 4 + j * 64);
            char4v v = { c8row[id.x], c8row[id.y], c8row[id.z], c8row[id.w] };
            *(char4v*)(btl + j * 1024 + b * 64 + m * 4) = v;
        }
    }
    __syncthreads();

    // ---- i8-native D-layout probe (R3-proven) ----
    int rowD[4], colD[4];
    {
        const int cb  = c * 0x01010101;
        const int hot = (q == 0) ? 1 : 0;
        int4v aLab = {cb, cb, cb, cb};
        int4v oneh = {hot, 0, 0, 0};
        int4v dR = {0, 0, 0, 0}, dC = {0, 0, 0, 0};
        dR = __builtin_amdgcn_mfma_i32_16x16x64_i8(aLab, oneh, dR, 0, 0, 0);
        dC = __builtin_amdgcn_mfma_i32_16x16x64_i8(oneh, aLab, dC, 0, 0, 0);
        #pragma unroll
        for (int r = 0; r < 4; ++r) { rowD[r] = dR[r]; colD[r] = dC[r]; }
    }

    int4v acc0[NDIG], acc1[NDIG], accS = (int4v)0;
    #pragma unroll
    for (int j = 0; j < NDIG; ++j) { acc0[j] = (int4v)0; acc1[j] = (int4v)0; }

    const size_t DP = (size_t)NN * DD;
    const signed char* ab = Wd5 + (size_t)nsup * 65536 + c * 64 + q * 16;
    const signed char* bb = btl + c * 64 + q * 16;       // LDS B base

    const int4v ones = {0x01010101, 0x01010101, 0x01010101, 0x01010101};
    const int ck0 = wq * 8;

    // ping-pong A stages (R5 structure); B read per-chunk from LDS
    int4v A0[NDIG], A1[NDIG];
    int4v N0[NDIG], N1[NDIG];

    {
        const signed char* ap = ab + (size_t)ck0 * 2048;
        #pragma unroll
        for (int j = 0; j < NDIG; ++j) {
            A0[j] = *(const int4v*)(ap + (size_t)j * DP);
            A1[j] = *(const int4v*)(ap + (size_t)j * DP + 1024);
        }
    }

    #pragma unroll 1
    for (int u = 0; u < 3; ++u) {        // chunks 2u, 2u+1 for u=0..2
        {
            const signed char* ap = ab + (size_t)(ck0 + 2 * u + 1) * 2048;
            #pragma unroll
            for (int j = 0; j < NDIG; ++j) {
                N0[j] = *(const int4v*)(ap + (size_t)j * DP);
                N1[j] = *(const int4v*)(ap + (size_t)j * DP + 1024);
            }
        }
        {
            int4v Bv = *(const int4v*)(bb + (size_t)(ck0 + 2 * u) * 1024);
            #pragma unroll
            for (int j = 0; j < NDIG; ++j) {
                acc0[j] = __builtin_amdgcn_mfma_i32_16x16x64_i8(A0[j], Bv, acc0[j], 0, 0, 0);
                acc1[j] = __builtin_amdgcn_mfma_i32_16x16x64_i8(A1[j], Bv, acc1[j], 0, 0, 0);
            }
            accS = __builtin_amdgcn_mfma_i32_16x16x64_i8(ones, Bv, accS, 0, 0, 0);
        }
        {
            const signed char* ap = ab + (size_t)(ck0 + 2 * u + 2) * 2048;
            #pragma unroll
            for (int j = 0; j < NDIG; ++j) {
                A0[j] = *(const int4v*)(ap + (size_t)j * DP);
                A1[j] = *(const int4v*)(ap + (size_t)j * DP + 1024);
            }
        }
        {
            int4v Bv = *(const int4v*)(bb + (size_t)(ck0 + 2 * u + 1) * 1024);
            #pragma unroll
            for (int j = 0; j < NDIG; ++j) {
                acc0[j] = __builtin_amdgcn_mfma_i32_16x16x64_i8(N0[j], Bv, acc0[j], 0, 0, 0);
                acc1[j] = __builtin_amdgcn_mfma_i32_16x16x64_i8(N1[j], Bv, acc1[j], 0, 0, 0);
            }
            accS = __builtin_amdgcn_mfma_i32_16x16x64_i8(ones, Bv, accS, 0, 0, 0);
        }
    }
    // epilogue: A-stage holds chunk 6; prefetch chunk 7, compute both
    {
        const signed char* ap = ab + (size_t)(ck0 + 7) * 2048;
        #pragma unroll
        for (int j = 0; j < NDIG; ++j) {
            N0[j] = *(const int4v*)(ap + (size_t)j * DP);
            N1[j] = *(const int4v*)(ap + (size_t)j * DP + 1024);
        }
    }
    {
        int4v Bv = *(const int4v*)(bb + (size_t)(ck0 + 6) * 1024);
        #pragma unroll
        for (int j = 0; j < NDIG; ++j) {
            acc0[j] = __builtin_amdgcn_mfma_i32_16x16x64_i8(A0[j], Bv, acc0[j], 0, 0, 0);
            acc1[j] = __builtin_amdgcn_mfma_i32_16x16x64_i8(A1[j], Bv, acc1[j], 0, 0, 0);
        }
        accS = __builtin_amdgcn_mfma_i32_16x16x64_i8(ones, Bv, accS, 0, 0, 0);
    }
    {
        int4v Bv = *(const int4v*)(bb + (size_t)(ck0 + 7) * 1024);
        #pragma unroll
        for (int j = 0; j < NDIG; ++j) {
            acc0[j] = __builtin_amdgcn_mfma_i32_16x16x64_i8(N0[j], Bv, acc0[j], 0, 0, 0);
            acc1[j] = __builtin_amdgcn_mfma_i32_16x16x64_i8(N1[j], Bv, acc1[j], 0, 0, 0);
        }
        accS = __builtin_amdgcn_mfma_i32_16x16x64_i8(ones, Bv, accS, 0, 0, 0);
    }

    // digit recombination: exact powers of two; bias 2^34 removed via accS
    const double S0 = 0x1p-33, S1 = 0x1p-26, S2 = 0x1p-19,
                 S3 = 0x1p-12, S4 = 0x1p-5;
    {
        double* my = red + ((size_t)wq * 64 + lane) * 8;
        #pragma unroll
        for (int r = 0; r < 4; ++r) {
            double corr = 2.0 * (double)accS[r];
            my[r]     = S0 * (double)acc0[0][r] + S1 * (double)acc0[1][r]
                      + S2 * (double)acc0[2][r] + S3 * (double)acc0[3][r]
                      + S4 * (double)acc0[4][r] - corr;
            my[4 + r] = S0 * (double)acc1[0][r] + S1 * (double)acc1[1][r]
                      + S2 * (double)acc1[2][r] + S3 * (double)acc1[3][r]
                      + S4 * (double)acc1[4][r] - corr;
        }
    }
    __syncthreads();
    if (wq < 2) {
        const int off = wq * 4;
        double a[4];
        #pragma unroll
        for (int r = 0; r < 4; ++r) {
            a[r] =  red[((size_t)0 * 64 + lane) * 8 + off + r];
            a[r] += red[((size_t)1 * 64 + lane) * 8 + off + r];
            a[r] += red[((size_t)2 * 64 + lane) * 8 + off + r];
            a[r] += red[((size_t)3 * 64 + lane) * 8 + off + r];
        }

        const double th = (double)thresholds[l];
        const int T = *Tptr;
        const double invT = 1.0 / (double)T;
        const float sc = isLast ? 1.0f : (1.0f / (float)T);
        double m0 = 0., m1 = 0., m2 = 0., m3 = 0.;
        int c0 = 0, c1 = 0, c2 = 0, c3 = 0;
        const double v0 = a[0] * invT, v1 = a[1] * invT,
                     v2 = a[2] * invT, v3 = a[3] * invT;
        for (int tt = 0; tt < T; ++tt) {
            m0 += v0; if (m0 > th) { c0++; m0 -= th; }
            m1 += v1; if (m1 > th) { c1++; m1 -= th; }
            m2 += v2; if (m2 > th) { c2++; m2 -= th; }
            m3 += v3; if (m3 > th) { c3++; m3 -= th; }
        }
        int cnt[4] = {c0, c1, c2, c3};
        #pragma unroll
        for (int r = 0; r < 4; ++r) {
            int n = n0 + 16 * wq + rowD[r];
            int b = btile * 16 + colD[r];
            dst[(size_t)n * BB + b] = (float)cnt[r] * sc;
            if (c8T) c8T[(size_t)b * NN + n] = (signed char)cnt[r];
        }
    }
}

// ---------------------------------------------------------------------------
// Output gather: out[b, o] = cntT[out_idx[o]][b]
// ---------------------------------------------------------------------------
__global__ __launch_bounds__(256) void out_kernel(
    const float* __restrict__ cntT, const int* __restrict__ out_idx,
    float* __restrict__ out)
{
    int i = blockIdx.x * 256 + threadIdx.x;   // over BB*OUTN
    int b = i >> 10;
    int o = i & 1023;
    out[i] = cntT[(size_t)out_idx[o] * BB + b];
}

extern "C" void kernel_launch(void* const* d_in, const int* in_sizes, int n_in,
                              void* d_out, int out_size, void* d_ws, size_t ws_size,
                              hipStream_t stream)
{
    const float* x    = (const float*)d_in[0];
    const float* W    = (const float*)d_in[1];
    const float* thr  = (const float*)d_in[2];
    const int*   axon = (const int*)d_in[3];
    const int*   oidx = (const int*)d_in[4];
    const int*   Tptr = (const int*)d_in[5];
    float* out = (float*)d_out;

    const size_t DP = (size_t)NN * DD;
    char* ws = (char*)d_ws;
    float* mA   = (float*)(ws + (1u << 20));          // 1 MB ping
    float* mB   = (float*)(ws + (2u << 20));          // 1 MB pong
    float* cntT = (float*)(ws + (3u << 20));          // 1 MB
    signed char* c8A = (signed char*)(ws + (4u << 20));               // 256 KB [b][n]
    signed char* c8B = (signed char*)(ws + (4u << 20) + (256u << 10));// 256 KB
    signed char* Wd  = (signed char*)(ws + (5u << 20));               // 60 MB tiled planes

    const int useI8 = (ws_size >= ((size_t)80 << 20)) ? 1 : 0;

    if (!useI8) {
        // fallback: proven all-fp64 path (5 launches; l=0 reads x directly)
        const float* srcs[LL] = { x, mA, mB, mA };
        float*       dsts[LL] = { mA, mB, mA, cntT };
        for (int l = 0; l < LL; ++l) {
            layer_kernel<<<512, 256, 0, stream>>>(
                srcs[l], axon + (size_t)l * DD,
                (l == 0) ? 1 : BB, (l == 0) ? DD : 1,
                W + (size_t)l * NN * DD, thr, l, Tptr,
                dsts[l], nullptr, (l == LL - 1) ? 1 : 0);
        }
    } else {
        // 1) digitize W for layers 1..3 (one launch, tiled planes)
        wdig5_kernel<<<(int)(3 * (DP / 4) / 256), 256, 0, stream>>>(W + DP, Wd);

        // 2) layer 0: fp64 MFMA path reading x directly (gather0 fused away)
        layer_kernel<<<512, 256, 0, stream>>>(
            x, axon, 1, DD, W, thr, 0, Tptr, mA, c8A, 0);

        // 3-5) layers 1..3: integer path with fused in-kernel gather
        layer_i8_kernel<<<512, 256, 0, stream>>>(
            c8A, axon + 1 * DD, Wd + 0 * 5 * DP, thr, 1, Tptr, mB, c8B, 0);
        layer_i8_kernel<<<512, 256, 0, stream>>>(
            c8B, axon + 2 * DD, Wd + 1 * 5 * DP, thr, 2, Tptr, mA, c8A, 0);
        layer_i8_kernel<<<512, 256, 0, stream>>>(
            c8A, axon + 3 * DD, Wd + 2 * 5 * DP, thr, 3, Tptr, cntT, nullptr, 1);

        // 6) output gather
        out_kernel<<<(BB * OUTN) / 256, 256, 0, stream>>>(cntT, oidx, out);
    }
}

// Round 7
// 215.085 us; speedup vs baseline: 1.2324x; 1.2324x over previous
//
#include <hip/hip_runtime.h>

// Problem constants
#define BB   128
#define DD   2048
#define NN   2048
#define LL   4
#define OUTN 1024
#define JBQ  32                // 16-k groups per K-quarter (512 k / quarter)
#define NDIG 5                 // base-128 digit planes (bias 2^34, scale 2^-33)

#define NWDIG 12288            // wdig blocks: 3*DP/4/256
#define NG0   1024             // gather0 blocks: DD*BB/256
#define NCSR  4                // inverse-map builds (axon1..3, out_idx)

typedef double double4v __attribute__((ext_vector_type(4)));
typedef int    int4v    __attribute__((ext_vector_type(4)));
typedef char   char4v   __attribute__((ext_vector_type(4)));

// ---------------------------------------------------------------------------
// PREP kernel (one launch): blockIdx-partitioned independent producers.
//  [0, NWDIG)           : W digitization (R4-proven tiled 5-plane layout)
//  [NWDIG, +NG0)        : At[k][b] = x[b, axon0[k]]   (layer-0 transpose)
//  [NWDIG+NG0, +NCSR)   : CSR inverse maps: for map m, bins n in [0,2048):
//                         lst[off[n]..off[n+1]) = { e : idx[e] == n }
//                         m=0..2 -> axon[m+1] (DD entries), m=3 -> out_idx.
// ---------------------------------------------------------------------------
__global__ __launch_bounds__(256) void prep_kernel(
    const float* __restrict__ W1,      // W + DP (layers 1..3)
    const float* __restrict__ x,
    const int*   __restrict__ axon,
    const int*   __restrict__ oidx,
    signed char* __restrict__ Wd,
    float*       __restrict__ At,
    int*         __restrict__ off,     // [4][2052]
    int*         __restrict__ lst)     // [4][2048]
{
    __shared__ int hist[2048];
    __shared__ int part[256];

    const int t  = threadIdx.x;
    const int bk = blockIdx.x;
    const size_t DP = (size_t)NN * DD;

    if (bk < NWDIG) {
        // ---- W digitization (R4-proven) ----
        size_t i  = (size_t)bk * 256 + t;          // over 3*DP/4
        int    l  = (int)(i / (DP / 4));
        size_t e4 = i - (size_t)l * (DP / 4);
        int n = (int)(e4 >> 9);
        int k = (int)(e4 & 511) * 4;
        float4 w = *(const float4*)(W1 + (size_t)l * DP + (size_t)n * DD + k);
        const float wv[4] = {w.x, w.y, w.z, w.w};
        unsigned long long V[4];
        #pragma unroll
        for (int e = 0; e < 4; ++e)
            V[e] = (unsigned long long)(__double2ll_rn((double)wv[e] * 0x1p33)
                                        + (1LL << 34));
        signed char* base = Wd + (size_t)l * 5 * DP
                          + (size_t)(n >> 5) * 65536 + (size_t)(k >> 6) * 2048
                          + (n & 31) * 64 + (k & 63);
        #pragma unroll
        for (int j = 0; j < NDIG; ++j) {
            char4v p = { (char)((V[0] >> (7 * j)) & 127),
                         (char)((V[1] >> (7 * j)) & 127),
                         (char)((V[2] >> (7 * j)) & 127),
                         (char)((V[3] >> (7 * j)) & 127) };
            *(char4v*)(base + (size_t)j * DP) = p;
        }
        return;
    }
    if (bk < NWDIG + NG0) {
        // ---- layer-0 transpose gather ----
        int i = (bk - NWDIG) * 256 + t;            // over DD*BB
        int k = i >> 7;
        int b = i & 127;
        At[i] = x[b * DD + axon[k]];
        return;
    }
    // ---- CSR inverse-map build (4 blocks) ----
    {
        const int m   = bk - (NWDIG + NG0);
        const int* ip = (m < 3) ? (axon + (size_t)(m + 1) * DD) : oidx;
        const int cnt = (m < 3) ? DD : OUTN;
        int* offG = off + m * 2052;
        int* lstG = lst + m * 2048;

        for (int i = t; i < 2048; i += 256) hist[i] = 0;
        __syncthreads();
        for (int e = t; e < cnt; e += 256) atomicAdd(&hist[ip[e]], 1);
        __syncthreads();

        // exclusive scan over 2048 bins (8 bins/thread + block scan)
        const int b0 = t * 8;
        int s = 0;
        #pragma unroll
        for (int i = 0; i < 8; ++i) s += hist[b0 + i];
        part[t] = s;
        __syncthreads();
        for (int d = 1; d < 256; d <<= 1) {
            int v = (t >= d) ? part[t - d] : 0;
            __syncthreads();
            part[t] += v;
            __syncthreads();
        }
        int base = part[t] - s;
        #pragma unroll
        for (int i = 0; i < 8; ++i) {
            int h = hist[b0 + i];
            offG[b0 + i] = base;
            hist[b0 + i] = base;        // becomes slot counter
            base += h;
        }
        if (t == 255) offG[2048] = base;
        __syncthreads();
        for (int e = t; e < cnt; e += 256) {
            int n = ip[e];
            int pos = atomicAdd(&hist[n], 1);
            lstG[pos] = e;
        }
    }
}

// ---------------------------------------------------------------------------
// Barrier-free fused layer kernel, fp64 MFMA path (layer 0 / fallback).
// Interior = R0..R5-proven structure (generalized src strides for fallback).
// Epilogue outputs (any subset): float dst, CSR scatter to next-layer g8
// (tiled i8 B-buffer), CSR scatter to out.
// ---------------------------------------------------------------------------
__global__ __launch_bounds__(256, 2) void layer_kernel(
    const float* __restrict__ src,
    const int*   __restrict__ idx,    // nullptr => identity rows
    int sR, int sB,
    const float* __restrict__ Wl,     // [n][k] row-major
    const float* __restrict__ thresholds, int l,
    const int*   __restrict__ Tptr,
    float* __restrict__ dst,
    const int* __restrict__ goff, const int* __restrict__ glst,
    signed char* __restrict__ g8n,
    const int* __restrict__ ooff, const int* __restrict__ olst,
    float* __restrict__ outp,
    int isLast)
{
    __shared__ double red[4 * 64 * 8];   // 16 KB, epilogue only

    const int t    = threadIdx.x;
    const int wq   = t >> 6;             // K-quarter 0..3
    const int lane = t & 63;
    const int q    = lane >> 4;
    const int c    = lane & 15;

    const int g     = blockIdx.x;        // 0..511
    const int btile = (g >> 3) & 7;      // b-replicas of one nsup: same XCD (mod 8)
    const int nsup  = (g & 7) | ((g >> 6) << 3);
    const int n0    = nsup * 32;
    const int bcol  = btile * 16 + c;
    const size_t bo = (size_t)bcol * sB; // source column offset

    // ---- runtime D-layout probe (layout-agnostic epilogue), f64-native ----
    double4v pr = {0., 0., 0., 0.}, pcv = {0., 0., 0., 0.};
    pr  = __builtin_amdgcn_mfma_f64_16x16x4f64(0.25 * (double)c, 1.0, pr, 0, 0, 0);
    pcv = __builtin_amdgcn_mfma_f64_16x16x4f64(0.25, (double)c, pcv, 0, 0, 0);
    int rowD[4], colD[4];
    #pragma unroll
    for (int r = 0; r < 4; ++r) {
        rowD[r] = (int)(pr[r] + 0.25);
        colD[r] = (int)(pcv[r] + 0.25);
    }

    double4v acc0[4] = {{0.,0.,0.,0.},{0.,0.,0.,0.},{0.,0.,0.,0.},{0.,0.,0.,0.}};
    double4v acc1[4] = {{0.,0.,0.,0.},{0.,0.,0.,0.},{0.,0.,0.,0.},{0.,0.,0.,0.}};

    const int    kbase = wq * (DD / 4);  // 512 k per quarter
    const float* wb0   = Wl + (size_t)(n0 + c) * DD + kbase + 4 * q;
    const float* wb1   = wb0 + (size_t)16 * DD;
    const int*   ibase = idx ? (idx + kbase + 4 * q) : nullptr;

    float4 wv0[4], wv1[4];   // W pipelines (2 n-rows), static slots
    float4 sv[4];            // src pipeline, static slots
    int4   iv[4];            // idx pipeline, static slots

    // ---- prologue: groups 0..3 ----
    #pragma unroll
    for (int p = 0; p < 4; ++p) {
        wv0[p] = *(const float4*)(wb0 + 16 * p);
        wv1[p] = *(const float4*)(wb1 + 16 * p);
    }
    #pragma unroll
    for (int p = 0; p < 4; ++p) {
        int r0, r1, r2, r3;
        if (ibase) {
            int4 iv0 = *(const int4*)(ibase + 16 * p);
            r0 = iv0.x; r1 = iv0.y; r2 = iv0.z; r3 = iv0.w;
        } else {
            int kb = kbase + 16 * p + 4 * q;
            r0 = kb; r1 = kb + 1; r2 = kb + 2; r3 = kb + 3;
        }
        sv[p].x = src[(size_t)r0 * sR + bo];
        sv[p].y = src[(size_t)r1 * sR + bo];
        sv[p].z = src[(size_t)r2 * sR + bo];
        sv[p].w = src[(size_t)r3 * sR + bo];
    }
    if (ibase) {
        #pragma unroll
        for (int p = 0; p < 4; ++p) iv[p] = *(const int4*)(ibase + 16 * (4 + p));
    }

    // ---- barrier-free K-loop: 8 iterations x 4 static-slot groups ----
    for (int u = 0; u < JBQ / 4; ++u) {
        #pragma unroll
        for (int gg = 0; gg < 4; ++gg) {
            float4 w0 = wv0[gg];
            float4 w1 = wv1[gg];
            float4 s  = sv[gg];

            int jn = 4 * u + 4 + gg; if (jn > JBQ - 1) jn = JBQ - 1;
            wv0[gg] = *(const float4*)(wb0 + 16 * jn);
            wv1[gg] = *(const float4*)(wb1 + 16 * jn);

            int r0, r1, r2, r3;
            if (ibase) {
                int4 ivv = iv[gg];
                r0 = ivv.x; r1 = ivv.y; r2 = ivv.z; r3 = ivv.w;
            } else {
                int kb = kbase + 16 * jn + 4 * q;
                r0 = kb; r1 = kb + 1; r2 = kb + 2; r3 = kb + 3;
            }
            sv[gg].x = src[(size_t)r0 * sR + bo];
            sv[gg].y = src[(size_t)r1 * sR + bo];
            sv[gg].z = src[(size_t)r2 * sR + bo];
            sv[gg].w = src[(size_t)r3 * sR + bo];

            if (ibase) {
                int jm = 4 * u + 8 + gg; if (jm > JBQ - 1) jm = JBQ - 1;
                iv[gg] = *(const int4*)(ibase + 16 * jm);
            }

            acc0[0] = __builtin_amdgcn_mfma_f64_16x16x4f64((double)w0.x, (double)s.x, acc0[0], 0, 0, 0);
            acc1[0] = __builtin_amdgcn_mfma_f64_16x16x4f64((double)w1.x, (double)s.x, acc1[0], 0, 0, 0);
            acc0[1] = __builtin_amdgcn_mfma_f64_16x16x4f64((double)w0.y, (double)s.y, acc0[1], 0, 0, 0);
            acc1[1] = __builtin_amdgcn_mfma_f64_16x16x4f64((double)w1.y, (double)s.y, acc1[1], 0, 0, 0);
            acc0[2] = __builtin_amdgcn_mfma_f64_16x16x4f64((double)w0.z, (double)s.z, acc0[2], 0, 0, 0);
            acc1[2] = __builtin_amdgcn_mfma_f64_16x16x4f64((double)w1.z, (double)s.z, acc1[2], 0, 0, 0);
            acc0[3] = __builtin_amdgcn_mfma_f64_16x16x4f64((double)w0.w, (double)s.w, acc0[3], 0, 0, 0);
            acc1[3] = __builtin_amdgcn_mfma_f64_16x16x4f64((double)w1.w, (double)s.w, acc1[3], 0, 0, 0);
        }
    }

    double4v a0 = (acc0[0] + acc0[1]) + (acc0[2] + acc0[3]);
    double4v a1 = (acc1[0] + acc1[1]) + (acc1[2] + acc1[3]);

    {
        double* my = red + ((size_t)wq * 64 + lane) * 8;
        #pragma unroll
        for (int r = 0; r < 4; ++r) { my[r] = a0[r]; my[4 + r] = a1[r]; }
    }
    __syncthreads();
    if (wq < 2) {
        const int off = wq * 4;
        double a[4];
        #pragma unroll
        for (int r = 0; r < 4; ++r) {
            a[r] =  red[((size_t)0 * 64 + lane) * 8 + off + r];
            a[r] += red[((size_t)1 * 64 + lane) * 8 + off + r];
            a[r] += red[((size_t)2 * 64 + lane) * 8 + off + r];
            a[r] += red[((size_t)3 * 64 + lane) * 8 + off + r];
        }

        const double th = (double)thresholds[l];
        const int T = *Tptr;
        const float sc = isLast ? 1.0f : (1.0f / (float)T);
        double m0 = 0., m1 = 0., m2 = 0., m3 = 0.;
        int c0 = 0, c1 = 0, c2 = 0, c3 = 0;
        for (int tt = 0; tt < T; ++tt) {
            m0 += a[0]; if (m0 > th) { c0++; m0 -= th; }
            m1 += a[1]; if (m1 > th) { c1++; m1 -= th; }
            m2 += a[2]; if (m2 > th) { c2++; m2 -= th; }
            m3 += a[3]; if (m3 > th) { c3++; m3 -= th; }
        }
        int cnt[4] = {c0, c1, c2, c3};
        #pragma unroll
        for (int r = 0; r < 4; ++r) {
            int n = n0 + 16 * wq + rowD[r];
            int b = btile * 16 + colD[r];
            if (dst)  dst[(size_t)n * BB + b] = (float)cnt[r] * sc;
            if (goff) {
                for (int j = goff[n]; j < goff[n + 1]; ++j) {
                    int k = glst[j];
                    g8n[(size_t)(k >> 6) * 8192 + b * 64 + (k & 63)] =
                        (signed char)cnt[r];
                }
            }
            if (ooff) {
                for (int j = ooff[n]; j < ooff[n + 1]; ++j)
                    outp[(size_t)b * OUTN + olst[j]] = (float)cnt[r];
            }
        }
    }
}

// ---------------------------------------------------------------------------
// Integer-exact layer kernel (layers 1..3), base-128 digits, TILED operands.
// Interior = R5-proven (register ping-pong A, global tiled B).
// Epilogue: CSR scatter to next-layer g8 OR to out (last layer).
// ---------------------------------------------------------------------------
__global__ __launch_bounds__(256, 2) void layer_i8_kernel(
    const signed char* __restrict__ B8,    // g8 tiled [ck:32][b:128][kk:64]
    const signed char* __restrict__ Wd5,   // 5 tiled digit planes, stride DP
    const float* __restrict__ thresholds, int l,
    const int*   __restrict__ Tptr,
    const int* __restrict__ goff, const int* __restrict__ glst,
    signed char* __restrict__ g8n,
    const int* __restrict__ ooff, const int* __restrict__ olst,
    float* __restrict__ outp,
    int isLast)
{
    __shared__ double red[4 * 64 * 8];

    const int t    = threadIdx.x;
    const int wq   = t >> 6;
    const int lane = t & 63;
    const int q    = lane >> 4;
    const int c    = lane & 15;

    const int g     = blockIdx.x;
    const int btile = (g >> 3) & 7;
    const int nsup  = (g & 7) | ((g >> 6) << 3);
    const int n0    = nsup * 32;
    const int bcol  = btile * 16 + c;

    // ---- i8-native D-layout probe (R3-proven) ----
    int rowD[4], colD[4];
    {
        const int cb  = c * 0x01010101;
        const int hot = (q == 0) ? 1 : 0;
        int4v aLab = {cb, cb, cb, cb};
        int4v oneh = {hot, 0, 0, 0};
        int4v dR = {0, 0, 0, 0}, dC = {0, 0, 0, 0};
        dR = __builtin_amdgcn_mfma_i32_16x16x64_i8(aLab, oneh, dR, 0, 0, 0);
        dC = __builtin_amdgcn_mfma_i32_16x16x64_i8(oneh, aLab, dC, 0, 0, 0);
        #pragma unroll
        for (int r = 0; r < 4; ++r) { rowD[r] = dR[r]; colD[r] = dC[r]; }
    }

    int4v acc0[NDIG], acc1[NDIG], accS = (int4v)0;
    #pragma unroll
    for (int j = 0; j < NDIG; ++j) { acc0[j] = (int4v)0; acc1[j] = (int4v)0; }

    const size_t DP = (size_t)NN * DD;
    const signed char* ab = Wd5 + (size_t)nsup * 65536 + c * 64 + q * 16;
    const signed char* bb = B8 + bcol * 64 + q * 16;

    const int4v ones = {0x01010101, 0x01010101, 0x01010101, 0x01010101};
    const int ck0 = wq * 8;

    int4v A0[NDIG], A1[NDIG], Bv;
    int4v N0[NDIG], N1[NDIG], Nb;

    {
        const signed char* ap = ab + (size_t)ck0 * 2048;
        #pragma unroll
        for (int j = 0; j < NDIG; ++j) {
            A0[j] = *(const int4v*)(ap + (size_t)j * DP);
            A1[j] = *(const int4v*)(ap + (size_t)j * DP + 1024);
        }
        Bv = *(const int4v*)(bb + (size_t)ck0 * 8192);
    }

    #pragma unroll 1
    for (int u = 0; u < 3; ++u) {        // chunks 2u, 2u+1 for u=0..2
        {
            const signed char* ap = ab + (size_t)(ck0 + 2 * u + 1) * 2048;
            #pragma unroll
            for (int j = 0; j < NDIG; ++j) {
                N0[j] = *(const int4v*)(ap + (size_t)j * DP);
                N1[j] = *(const int4v*)(ap + (size_t)j * DP + 1024);
            }
            Nb = *(const int4v*)(bb + (size_t)(ck0 + 2 * u + 1) * 8192);
        }
        #pragma unroll
        for (int j = 0; j < NDIG; ++j) {
            acc0[j] = __builtin_amdgcn_mfma_i32_16x16x64_i8(A0[j], Bv, acc0[j], 0, 0, 0);
            acc1[j] = __builtin_amdgcn_mfma_i32_16x16x64_i8(A1[j], Bv, acc1[j], 0, 0, 0);
        }
        accS = __builtin_amdgcn_mfma_i32_16x16x64_i8(ones, Bv, accS, 0, 0, 0);
        {
            const signed char* ap = ab + (size_t)(ck0 + 2 * u + 2) * 2048;
            #pragma unroll
            for (int j = 0; j < NDIG; ++j) {
                A0[j] = *(const int4v*)(ap + (size_t)j * DP);
                A1[j] = *(const int4v*)(ap + (size_t)j * DP + 1024);
            }
            Bv = *(const int4v*)(bb + (size_t)(ck0 + 2 * u + 2) * 8192);
        }
        #pragma unroll
        for (int j = 0; j < NDIG; ++j) {
            acc0[j] = __builtin_amdgcn_mfma_i32_16x16x64_i8(N0[j], Nb, acc0[j], 0, 0, 0);
            acc1[j] = __builtin_amdgcn_mfma_i32_16x16x64_i8(N1[j], Nb, acc1[j], 0, 0, 0);
        }
        accS = __builtin_amdgcn_mfma_i32_16x16x64_i8(ones, Nb, accS, 0, 0, 0);
    }
    {
        const signed char* ap = ab + (size_t)(ck0 + 7) * 2048;
        #pragma unroll
        for (int j = 0; j < NDIG; ++j) {
            N0[j] = *(const int4v*)(ap + (size_t)j * DP);
            N1[j] = *(const int4v*)(ap + (size_t)j * DP + 1024);
        }
        Nb = *(const int4v*)(bb + (size_t)(ck0 + 7) * 8192);
    }
    #pragma unroll
    for (int j = 0; j < NDIG; ++j) {
        acc0[j] = __builtin_amdgcn_mfma_i32_16x16x64_i8(A0[j], Bv, acc0[j], 0, 0, 0);
        acc1[j] = __builtin_amdgcn_mfma_i32_16x16x64_i8(A1[j], Bv, acc1[j], 0, 0, 0);
    }
    accS = __builtin_amdgcn_mfma_i32_16x16x64_i8(ones, Bv, accS, 0, 0, 0);
    #pragma unroll
    for (int j = 0; j < NDIG; ++j) {
        acc0[j] = __builtin_amdgcn_mfma_i32_16x16x64_i8(N0[j], Nb, acc0[j], 0, 0, 0);
        acc1[j] = __builtin_amdgcn_mfma_i32_16x16x64_i8(N1[j], Nb, acc1[j], 0, 0, 0);
    }
    accS = __builtin_amdgcn_mfma_i32_16x16x64_i8(ones, Nb, accS, 0, 0, 0);

    // digit recombination: exact powers of two; bias 2^34 removed via accS
    const double S0 = 0x1p-33, S1 = 0x1p-26, S2 = 0x1p-19,
                 S3 = 0x1p-12, S4 = 0x1p-5;
    {
        double* my = red + ((size_t)wq * 64 + lane) * 8;
        #pragma unroll
        for (int r = 0; r < 4; ++r) {
            double corr = 2.0 * (double)accS[r];
            my[r]     = S0 * (double)acc0[0][r] + S1 * (double)acc0[1][r]
                      + S2 * (double)acc0[2][r] + S3 * (double)acc0[3][r]
                      + S4 * (double)acc0[4][r] - corr;
            my[4 + r] = S0 * (double)acc1[0][r] + S1 * (double)acc1[1][r]
                      + S2 * (double)acc1[2][r] + S3 * (double)acc1[3][r]
                      + S4 * (double)acc1[4][r] - corr;
        }
    }
    __syncthreads();
    if (wq < 2) {
        const int off = wq * 4;
        double a[4];
        #pragma unroll
        for (int r = 0; r < 4; ++r) {
            a[r] =  red[((size_t)0 * 64 + lane) * 8 + off + r];
            a[r] += red[((size_t)1 * 64 + lane) * 8 + off + r];
            a[r] += red[((size_t)2 * 64 + lane) * 8 + off + r];
            a[r] += red[((size_t)3 * 64 + lane) * 8 + off + r];
        }

        const double th = (double)thresholds[l];
        const int T = *Tptr;
        const double invT = 1.0 / (double)T;
        double m0 = 0., m1 = 0., m2 = 0., m3 = 0.;
        int c0 = 0, c1 = 0, c2 = 0, c3 = 0;
        const double v0 = a[0] * invT, v1 = a[1] * invT,
                     v2 = a[2] * invT, v3 = a[3] * invT;
        for (int tt = 0; tt < T; ++tt) {
            m0 += v0; if (m0 > th) { c0++; m0 -= th; }
            m1 += v1; if (m1 > th) { c1++; m1 -= th; }
            m2 += v2; if (m2 > th) { c2++; m2 -= th; }
            m3 += v3; if (m3 > th) { c3++; m3 -= th; }
        }
        int cnt[4] = {c0, c1, c2, c3};
        #pragma unroll
        for (int r = 0; r < 4; ++r) {
            int n = n0 + 16 * wq + rowD[r];
            int b = btile * 16 + colD[r];
            if (goff) {
                for (int j = goff[n]; j < goff[n + 1]; ++j) {
                    int k = glst[j];
                    g8n[(size_t)(k >> 6) * 8192 + b * 64 + (k & 63)] =
                        (signed char)cnt[r];
                }
            }
            if (ooff) {
                for (int j = ooff[n]; j < ooff[n + 1]; ++j)
                    outp[(size_t)b * OUTN + olst[j]] = (float)cnt[r];
            }
        }
    }
}

// ---------------------------------------------------------------------------
// Output gather (fallback path only): out[b, o] = cntT[out_idx[o]][b]
// ---------------------------------------------------------------------------
__global__ __launch_bounds__(256) void out_kernel(
    const float* __restrict__ cntT, const int* __restrict__ out_idx,
    float* __restrict__ out)
{
    int i = blockIdx.x * 256 + threadIdx.x;   // over BB*OUTN
    int b = i >> 10;
    int o = i & 1023;
    out[i] = cntT[(size_t)out_idx[o] * BB + b];
}

extern "C" void kernel_launch(void* const* d_in, const int* in_sizes, int n_in,
                              void* d_out, int out_size, void* d_ws, size_t ws_size,
                              hipStream_t stream)
{
    const float* x    = (const float*)d_in[0];
    const float* W    = (const float*)d_in[1];
    const float* thr  = (const float*)d_in[2];
    const int*   axon = (const int*)d_in[3];
    const int*   oidx = (const int*)d_in[4];
    const int*   Tptr = (const int*)d_in[5];
    float* out = (float*)d_out;

    const size_t DP = (size_t)NN * DD;
    char* ws = (char*)d_ws;
    float* At   = (float*)ws;                         // 1 MB [2048][128]
    float* mA   = (float*)(ws + (1u << 20));          // 1 MB (fallback)
    float* mB   = (float*)(ws + (2u << 20));          // 1 MB (fallback)
    float* cntT = (float*)(ws + (3u << 20));          // 1 MB (fallback)
    signed char* g8A = (signed char*)(ws + (4u << 20));               // 256 KB tiled
    signed char* g8B = (signed char*)(ws + (4u << 20) + (256u << 10));// 256 KB tiled
    int* off = (int*)(ws + (4u << 20) + (512u << 10));                // 33 KB
    int* lst = (int*)(ws + (4u << 20) + (640u << 10));                // 32 KB
    signed char* Wd  = (signed char*)(ws + (5u << 20));               // 60 MB tiled planes

    const int useI8 = (ws_size >= ((size_t)80 << 20)) ? 1 : 0;

    if (!useI8) {
        // fallback: proven all-fp64 path (l=0 reads x directly; slow but safe)
        const float* srcs[LL] = { x, mA, mB, mA };
        float*       dsts[LL] = { mA, mB, mA, cntT };
        for (int l = 0; l < LL; ++l) {
            layer_kernel<<<512, 256, 0, stream>>>(
                srcs[l], axon + (size_t)l * DD,
                (l == 0) ? 1 : BB, (l == 0) ? DD : 1,
                W + (size_t)l * NN * DD, thr, l, Tptr,
                dsts[l], nullptr, nullptr, nullptr, nullptr, nullptr, nullptr,
                (l == LL - 1) ? 1 : 0);
        }
        out_kernel<<<(BB * OUTN) / 256, 256, 0, stream>>>(cntT, oidx, out);
        return;
    }

    // 1) prep: wdig + gather0 + CSR inverse maps (one launch)
    prep_kernel<<<NWDIG + NG0 + NCSR, 256, 0, stream>>>(
        W + DP, x, axon, oidx, Wd, At, off, lst);

    // 2) layer 0: fp64 path on At; epilogue scatters i8 counts into g8A
    layer_kernel<<<512, 256, 0, stream>>>(
        At, nullptr, BB, 1, W, thr, 0, Tptr,
        nullptr, off + 0 * 2052, lst + 0 * 2048, g8A,
        nullptr, nullptr, nullptr, 0);

    // 3-5) layers 1..3: i8 path; epilogues scatter to next g8 / to out
    layer_i8_kernel<<<512, 256, 0, stream>>>(
        g8A, Wd + 0 * 5 * DP, thr, 1, Tptr,
        off + 1 * 2052, lst + 1 * 2048, g8B,
        nullptr, nullptr, nullptr, 0);
    layer_i8_kernel<<<512, 256, 0, stream>>>(
        g8B, Wd + 1 * 5 * DP, thr, 2, Tptr,
        off + 2 * 2052, lst + 2 * 2048, g8A,
        nullptr, nullptr, nullptr, 0);
    layer_i8_kernel<<<512, 256, 0, stream>>>(
        g8A, Wd + 2 * 5 * DP, thr, 3, Tptr,
        nullptr, nullptr, nullptr,
        off + 3 * 2052, lst + 3 * 2048, out, 1);
}